// Round 8
// baseline (79.253 us; speedup 1.0000x reference)
//
#include <hip/hip_runtime.h>
#include <math.h>

#define KPTS 133
#define FPS (KPTS * 3)   // 399 floats per sample
#define SPW 16           // samples per wave (4 lanes each)
#define WPB 4            // waves per block (256 threads)

__device__ __forceinline__ float det3(float a0, float a1, float a2,
                                      float b0, float b1, float b2,
                                      float c0, float c1, float c2) {
    return a0 * (b1 * c2 - b2 * c1)
         - a1 * (b0 * c2 - b2 * c0)
         + a2 * (b0 * c1 - b1 * c0);
}

// 4 lanes per sample, 16 samples per wave, ZERO barriers / ZERO LDS.
// - moments: each lane does 33 unguarded stride-4 points + 1 masked tail;
//   2-stage value-splitting butterfly (12 shuffles) reduces all 16 moments
//   within each 4-lane group; 16 bpermute-broadcasts give every lane its
//   group's full moment set.
// - solve: every lane solves its group's Horn eigenproblem. Control flow is
//   uniform (fixed-trip loops + selects), so ONE issued instruction stream
//   serves 16 samples -> ~34 inst/sample, no divergence, no param broadcast.
// - residuals: re-read points from global (L2/L3-hot; HBM has 85% headroom).
// - wave reduce (6 shuffles) -> one float per wave; deterministic final
//   reduce kernel in fixed order.
__global__ __launch_bounds__(256, 4) void pa_mpjpe_kernel(
    const float* __restrict__ outp,   // (N,K,3) output
    const float* __restrict__ tgtp,   // (N,K,3) target
    float* __restrict__ wave_sums,
    int nsamp)
{
    const int lane = threadIdx.x & 63;
    const int wid  = threadIdx.x >> 6;
    const int gw   = blockIdx.x * WPB + wid;    // global wave id
    const int l4   = lane & 3;                  // lane within 4-lane group
    int s = gw * SPW + (lane >> 2);             // this group's sample
    const bool valid = (s < nsamp);
    if (!valid) s = 0;                          // clamp; contribution zeroed later

    const size_t sb = (size_t)s * FPS;
    const float* tb = tgtp + sb;
    const float* ob = outp + sb;

    // red: [0..2]=sum_t, [3..5]=sum_o, [6..14]=sum t_a*o_b (row-major), [15]=sum t.t
    float red[16];
    #pragma unroll
    for (int i = 0; i < 16; ++i) red[i] = 0.0f;

#define PA_ACC(t0, t1, t2, o0, o1, o2)                                  \
    red[0]  += (t0);        red[1]  += (t1);        red[2]  += (t2);    \
    red[3]  += (o0);        red[4]  += (o1);        red[5]  += (o2);    \
    red[6]  += (t0) * (o0); red[7]  += (t0) * (o1); red[8]  += (t0) * (o2); \
    red[9]  += (t1) * (o0); red[10] += (t1) * (o1); red[11] += (t1) * (o2); \
    red[12] += (t2) * (o0); red[13] += (t2) * (o1); red[14] += (t2) * (o2); \
    red[15] += (t0) * (t0) + (t1) * (t1) + (t2) * (t2);

    // points p = l4 + 4j, j = 0..32 (covers 0..131, unguarded), tail p=132
    #pragma unroll 4
    for (int j = 0; j < 33; ++j) {
        const int idx = 3 * (l4 + 4 * j);
        const float t0 = tb[idx + 0], t1 = tb[idx + 1], t2 = tb[idx + 2];
        const float o0 = ob[idx + 0], o1 = ob[idx + 1], o2 = ob[idx + 2];
        PA_ACC(t0, t1, t2, o0, o1, o2)
    }
    if (l4 == 0) {  // tail point 132
        const int idx = 3 * 132;
        const float t0 = tb[idx + 0], t1 = tb[idx + 1], t2 = tb[idx + 2];
        const float o0 = ob[idx + 0], o1 = ob[idx + 1], o2 = ob[idx + 2];
        PA_ACC(t0, t1, t2, o0, o1, o2)
    }
#undef PA_ACC

    // ---- 2-stage value-splitting butterfly within 4-lane group ----
    // After xor1: lane bit0=b holds pair-sums of moments {2m+b}.
    // After xor2: lane l4 holds group sums v4_[m] = moment (4m + l4).
    float v8[8];
    {
        const bool b = (lane & 1);
        #pragma unroll
        for (int m = 0; m < 8; ++m) {
            const float snd = b ? red[2 * m] : red[2 * m + 1];
            const float rcv = __shfl_xor(snd, 1, 64);
            v8[m] = (b ? red[2 * m + 1] : red[2 * m]) + rcv;
        }
    }
    float v4_[4];
    {
        const bool b = ((lane >> 1) & 1);
        #pragma unroll
        for (int m = 0; m < 4; ++m) {
            const float snd = b ? v8[2 * m] : v8[2 * m + 1];
            const float rcv = __shfl_xor(snd, 2, 64);
            v4_[m] = (b ? v8[2 * m + 1] : v8[2 * m]) + rcv;
        }
    }

    // broadcast: moment j lives on lane (gbase + (j&3)) in v4_[j>>2]
    const int gbase = lane & 60;
    float m_[16];
    #pragma unroll
    for (int j = 0; j < 16; ++j)
        m_[j] = __shfl(v4_[j >> 2], gbase + (j & 3), 64);

    // ---- Horn quaternion eigenproblem (uniform flow; selects only) ----
    const float invK = 1.0f / (float)KPTS;
    const float mu1x = m_[0] * invK, mu1y = m_[1] * invK, mu1z = m_[2] * invK;
    const float mu2x = m_[3] * invK, mu2y = m_[4] * invK, mu2z = m_[5] * invK;

    const float Sxx = m_[6]  - m_[0] * m_[3] * invK;
    const float Sxy = m_[7]  - m_[0] * m_[4] * invK;
    const float Sxz = m_[8]  - m_[0] * m_[5] * invK;
    const float Syx = m_[9]  - m_[1] * m_[3] * invK;
    const float Syy = m_[10] - m_[1] * m_[4] * invK;
    const float Syz = m_[11] - m_[1] * m_[5] * invK;
    const float Szx = m_[12] - m_[2] * m_[3] * invK;
    const float Szy = m_[13] - m_[2] * m_[4] * invK;
    const float Szz = m_[14] - m_[2] * m_[5] * invK;
    const float var1 = m_[15] - (m_[0] * m_[0] + m_[1] * m_[1] + m_[2] * m_[2]) * invK;

    const float N00 = Sxx + Syy + Szz;
    const float N01 = Syz - Szy, N02 = Szx - Sxz, N03 = Sxy - Syx;
    const float N11 = Sxx - Syy - Szz, N12 = Sxy + Syx, N13 = Szx + Sxz;
    const float N22 = -Sxx + Syy - Szz, N23 = Syz + Szy;
    const float N33 = -Sxx - Syy + Szz;

    const float trKtK = Sxx * Sxx + Sxy * Sxy + Sxz * Sxz
                      + Syx * Syx + Syy * Syy + Syz * Syz
                      + Szx * Szx + Szy * Szy + Szz * Szz;
    const float c2 = -2.0f * trKtK;
    const float detK = det3(Sxx, Sxy, Sxz, Syx, Syy, Syz, Szx, Szy, Szz);
    const float c1 = -8.0f * detK;
    const float c0 =
          N00 * det3(N11, N12, N13, N12, N22, N23, N13, N23, N33)
        - N01 * det3(N01, N12, N13, N02, N22, N23, N03, N23, N33)
        + N02 * det3(N01, N11, N13, N02, N12, N23, N03, N13, N33)
        - N03 * det3(N01, N11, N12, N02, N12, N22, N03, N13, N23);

    // Newton from guaranteed upper bound sqrt(3*trKtK) >= s1+s2+s3 >= lam_max
    float lam = sqrtf(fmaxf(3.0f * trKtK, 0.0f));
    #pragma unroll
    for (int it = 0; it < 10; ++it) {
        const float l2 = lam * lam;
        const float P  = (l2 + c2) * l2 + c1 * lam + c0;
        const float Pp = (4.0f * l2 + 2.0f * c2) * lam + c1;
        lam -= P / Pp;
    }

    const float M00 = N00 - lam, M11 = N11 - lam, M22 = N22 - lam, M33 = N33 - lam;
    const float a0 =  det3(M11, N12, N13, N12, M22, N23, N13, N23, M33);
    const float a1 = -det3(N01, N12, N13, N02, M22, N23, N03, N23, M33);
    const float a2 =  det3(N01, M11, N13, N02, N12, N23, N03, N13, M33);
    const float a3 = -det3(N01, M11, N12, N02, N12, M22, N03, N13, N23);
    const float b0 = -det3(N01, N02, N03, N12, M22, N23, N13, N23, M33);
    const float b1 =  det3(M00, N02, N03, N02, M22, N23, N03, N23, M33);
    const float b2 = -det3(M00, N01, N03, N02, N12, N23, N03, N13, M33);
    const float b3 =  det3(M00, N01, N02, N02, N12, M22, N03, N13, N23);
    const float na = a0 * a0 + a1 * a1 + a2 * a2 + a3 * a3;
    const float nb = b0 * b0 + b1 * b1 + b2 * b2 + b3 * b3;
    const bool pa_ = (na >= nb);
    float qw = pa_ ? a0 : b0;
    float qx = pa_ ? a1 : b1;
    float qy = pa_ ? a2 : b2;
    float qz = pa_ ? a3 : b3;
    const float qn = rsqrtf(fmaxf(qw * qw + qx * qx + qy * qy + qz * qz, 1e-30f));
    qw *= qn; qx *= qn; qy *= qn; qz *= qn;

    const float R00 = 1.0f - 2.0f * (qy * qy + qz * qz);
    const float R01 = 2.0f * (qx * qy - qw * qz);
    const float R02 = 2.0f * (qx * qz + qw * qy);
    const float R10 = 2.0f * (qx * qy + qw * qz);
    const float R11 = 1.0f - 2.0f * (qx * qx + qz * qz);
    const float R12 = 2.0f * (qy * qz - qw * qx);
    const float R20 = 2.0f * (qx * qz - qw * qy);
    const float R21 = 2.0f * (qy * qz + qw * qx);
    const float R22 = 1.0f - 2.0f * (qx * qx + qy * qy);

    const float trRK = R00 * Sxx + R01 * Syx + R02 * Szx
                     + R10 * Sxy + R11 * Syy + R12 * Szy
                     + R20 * Sxz + R21 * Syz + R22 * Szz;
    const float scale = trRK / var1;

    const float sR00 = scale * R00, sR01 = scale * R01, sR02 = scale * R02;
    const float sR10 = scale * R10, sR11 = scale * R11, sR12 = scale * R12;
    const float sR20 = scale * R20, sR21 = scale * R21, sR22 = scale * R22;
    const float tx = mu2x - (sR00 * mu1x + sR01 * mu1y + sR02 * mu1z);
    const float ty = mu2y - (sR10 * mu1x + sR11 * mu1y + sR12 * mu1z);
    const float tz = mu2z - (sR20 * mu1x + sR21 * mu1y + sR22 * mu1z);

    // ---- residual norms: re-read points (L2/L3-hot) ----
    float rsum = 0.0f;
#define PA_RES(t0, t1, t2, o0, o1, o2)                                   \
    {                                                                    \
        const float ax = sR00 * (t0) + sR01 * (t1) + sR02 * (t2) + tx;   \
        const float ay = sR10 * (t0) + sR11 * (t1) + sR12 * (t2) + ty;   \
        const float az = sR20 * (t0) + sR21 * (t1) + sR22 * (t2) + tz;   \
        const float dx = (o0) - ax;                                      \
        const float dy = (o1) - ay;                                      \
        const float dz = (o2) - az;                                      \
        rsum += sqrtf(dx * dx + dy * dy + dz * dz);                      \
    }

    #pragma unroll 4
    for (int j = 0; j < 33; ++j) {
        const int idx = 3 * (l4 + 4 * j);
        const float t0 = tb[idx + 0], t1 = tb[idx + 1], t2 = tb[idx + 2];
        const float o0 = ob[idx + 0], o1 = ob[idx + 1], o2 = ob[idx + 2];
        PA_RES(t0, t1, t2, o0, o1, o2)
    }
    if (l4 == 0) {  // tail point 132
        const int idx = 3 * 132;
        const float t0 = tb[idx + 0], t1 = tb[idx + 1], t2 = tb[idx + 2];
        const float o0 = ob[idx + 0], o1 = ob[idx + 1], o2 = ob[idx + 2];
        PA_RES(t0, t1, t2, o0, o1, o2)
    }
#undef PA_RES

    rsum = valid ? rsum : 0.0f;   // zero clamped samples (cndmask: NaN-safe)

    // wave total: group (xor 1,2) then cross-group (xor 4,8,16,32)
    rsum += __shfl_xor(rsum, 1, 64);
    rsum += __shfl_xor(rsum, 2, 64);
    rsum += __shfl_xor(rsum, 4, 64);
    rsum += __shfl_xor(rsum, 8, 64);
    rsum += __shfl_xor(rsum, 16, 64);
    rsum += __shfl_xor(rsum, 32, 64);

    if (lane == 0) wave_sums[gw] = rsum;
}

// Deterministic final reduction: one block, fixed summation order.
__global__ __launch_bounds__(256) void pa_reduce_kernel(
    const float* __restrict__ wave_sums, int n,
    float* __restrict__ out, float inv_total)
{
    __shared__ float sh[4];
    float v = 0.0f;
    for (int i = threadIdx.x; i < n; i += 256) v += wave_sums[i];
    #pragma unroll
    for (int off = 32; off >= 1; off >>= 1) v += __shfl_xor(v, off, 64);
    const int lane = threadIdx.x & 63;
    const int wid  = threadIdx.x >> 6;
    if (lane == 0) sh[wid] = v;
    __syncthreads();
    if (threadIdx.x == 0) out[0] = (sh[0] + sh[1] + sh[2] + sh[3]) * inv_total;
}

extern "C" void kernel_launch(void* const* d_in, const int* in_sizes, int n_in,
                              void* d_out, int out_size, void* d_ws, size_t ws_size,
                              hipStream_t stream) {
    const float* outp = (const float*)d_in[0];   // "output"
    const float* tgtp = (const float*)d_in[1];   // "target"
    const int nsamp   = in_sizes[0] / (KPTS * 3);
    const int nwaves  = (nsamp + SPW - 1) / SPW;
    const int nblocks = (nwaves + WPB - 1) / WPB;

    float* wsums = (float*)d_ws;

    pa_mpjpe_kernel<<<nblocks, 256, 0, stream>>>(outp, tgtp, wsums, nsamp);
    pa_reduce_kernel<<<1, 256, 0, stream>>>(
        wsums, nwaves, (float*)d_out,
        1.0f / ((float)nsamp * (float)KPTS));
}